// Round 13
// baseline (89.555 us; speedup 1.0000x reference)
//
#include <hip/hip_runtime.h>

// ============================================================================
// r13 = r12 (verified 81.2us) + per-block LDS staging of the molecule's atoms.
// Mechanism: VMEM load-issue reduction (the only lever that ever won: r7->r9
// removed 15 loads/thread = -14us). Inner loop: 4 scalar loads per b-atom ->
// 1 ds_read_b128. Records XOR-swizzled (slot = a ^ ((a>>3)&7)): lane stride
// is 4 records = 64B which would be 8-way bank conflict; swizzle -> 2-way
// (free, m136). Staging loads are 16B-aligned float4/int4 (8 insts/thread).
// No d_ws (r10's failure), ranks/thread stays 4 (r11's failure), plain stores
// (r8's failure). Blocks never cross molecules: kPPM = 1024 * 2047 exactly.
//   E = 2P = 33,538,048 directed pairs; layout idx0|idx1|dist|diff*3|valid.
//   d even: (j,i), diff=c[j]-c[i];  d odd: (i,j), diff=c[i]-c[j].
// ============================================================================

namespace r13 {

constexpr int kM = 8;
constexpr int kN = 2048;
constexpr int kPPM = kN * (kN - 1) / 2;     // 2,096,128 triu pairs per molecule
constexpr int kP   = kPPM * kM;             // 16,769,024 triu pairs total
constexpr long long E = 2LL * kP;           // 33,538,048 directed pairs
constexpr int kBlocksPerMol = kPPM / 1024;  // 2047 (exact)

typedef __attribute__((ext_vector_type(8))) unsigned short u16x8;
typedef __attribute__((ext_vector_type(4))) float f32x4;

__device__ __forceinline__ unsigned short f2bf(float f) {
    unsigned int u = __float_as_uint(f);
    u += 0x7FFFu + ((u >> 16) & 1u);        // round-to-nearest-even
    return (unsigned short)(u >> 16);
}

__device__ __forceinline__ int row_off(int i) {
    return (i * (2 * kN - 1 - i)) >> 1;
}

// bank-conflict swizzle: record group = slot%8; lane stride of 4 records
// would pin slot%8 to 2 values -> XOR in bits >=3 spreads to all 8 groups.
__device__ __forceinline__ int swz(int a) { return a ^ ((a >> 3) & 7); }

__global__ __launch_bounds__(256)
void fp_r13(const int* __restrict__ species,
            const float* __restrict__ coords,
            const int* __restrict__ cutw,
            unsigned short* __restrict__ out)
{
#pragma clang fp contract(off)
    __shared__ f32x4 atoms[kN];             // 32 KB: (x,y,z,species_bits)

    const int blk = blockIdx.x;
    const int tid = threadIdx.x;
    const int m   = blk / kBlocksPerMol;    // molecule of this block
    const int base = m * kN;

    // ---- stage molecule into LDS (8 VMEM loads/thread, all 16B-aligned) ----
    {
        const f32x4* csrc = (const f32x4*)(coords + 3LL * base); // 24576m B, aligned
        const int4*  ssrc = (const int4*)(species + base);
        f32x4 f[6];
#pragma unroll
        for (int v = 0; v < 6; ++v) f[v] = csrc[6 * tid + v];    // atoms 8t..8t+7
        const int4 s0 = ssrc[2 * tid];
        const int4 s1 = ssrc[2 * tid + 1];
        const int sp[8] = {s0.x, s0.y, s0.z, s0.w, s1.x, s1.y, s1.z, s1.w};
        const float* ff = (const float*)&f[0];
#pragma unroll
        for (int k = 0; k < 8; ++k) {                            // static idx only
            const int a = 8 * tid + k;
            f32x4 rec;
            rec.x = ff[3 * k + 0];
            rec.y = ff[3 * k + 1];
            rec.z = ff[3 * k + 2];
            rec.w = __int_as_float(sp[k]);
            atoms[swz(a)] = rec;
        }
    }
    __syncthreads();

    const int g  = blk * 256 + tid;         // group of 4 triu ranks (== r12's g)
    const int t0 = g * 4;
    const int r0 = t0 - m * kPPM;           // rank within molecule

    // invert triangular index (4095^2 = 16,769,025 exact in f32)
    const float s = (float)(16769025 - 8 * r0);
    int i = (int)floorf((4095.0f - sqrtf(s)) * 0.5f);
    i = min(max(i, 0), kN - 2);
    while (row_off(i) > r0) --i;
    while (row_off(i + 1) <= r0) ++i;
    int j = i + 1 + (r0 - row_off(i));

    // cutoff: robust decode (int32 / int64-low-word / float32)
    const int w0 = cutw[0];
    const float cutoff = (w0 > 0 && w0 < (1 << 20)) ? (float)w0 : __int_as_float(w0);

    // hoisted i-atom record from LDS (reloaded only on row wrap)
    f32x4 wa = atoms[swz(i)];
    unsigned short ba = f2bf((float)(base + i));

    u16x8 vi0, vi1, vd, vv;
    u16x8 vf0, vf1, vf2;
    unsigned short df[24];

#pragma unroll
    for (int k = 0; k < 4; ++k) {
        const f32x4 wb = atoms[swz(j)];     // one ds_read_b128

        const float dx = wa.x - wb.x;
        const float dy = wa.y - wb.y;
        const float dz = wa.z - wb.z;
        const float d2 = dx * dx + dy * dy + dz * dz;   // no FMA: match np exactly
        const float dist = sqrtf(d2);

        const bool dummy = (__float_as_int(wa.w) == -1) || (__float_as_int(wb.w) == -1);
        const bool valid = (dist <= cutoff) && !dummy;

        const unsigned short bb = f2bf((float)(base + j));
        const unsigned short bd = valid ? f2bf(dist) : (unsigned short)0;
        const unsigned short bv = valid ? (unsigned short)0x3F80 : (unsigned short)0;
        const unsigned short fx = valid ? f2bf(dx) : (unsigned short)0;   // fwd (i,j)
        const unsigned short fy = valid ? f2bf(dy) : (unsigned short)0;
        const unsigned short fz = valid ? f2bf(dz) : (unsigned short)0;
        const unsigned short gx = valid ? (unsigned short)(fx ^ 0x8000) : (unsigned short)0;
        const unsigned short gy = valid ? (unsigned short)(fy ^ 0x8000) : (unsigned short)0;
        const unsigned short gz = valid ? (unsigned short)(fz ^ 0x8000) : (unsigned short)0;

        // REV first (slot 2k): (j,i), diff = -(fwd); FWD second (slot 2k+1)
        vi0[2 * k]     = bb;  vi0[2 * k + 1] = ba;
        vi1[2 * k]     = ba;  vi1[2 * k + 1] = bb;
        vd[2 * k]      = bd;  vd[2 * k + 1]  = bd;
        vv[2 * k]      = bv;  vv[2 * k + 1]  = bv;
        df[6 * k + 0] = gx;  df[6 * k + 1] = gy;  df[6 * k + 2] = gz;
        df[6 * k + 3] = fx;  df[6 * k + 4] = fy;  df[6 * k + 5] = fz;

        // advance to next triu rank; reload hoisted i-record on row wrap
        ++j;
        if (j == kN) {
            ++i; j = i + 1;
            if (k < 3) {
                wa = atoms[swz(i)];
                ba = f2bf((float)(base + i));
            }
        }
    }

#pragma unroll
    for (int e = 0; e < 8; ++e) {
        vf0[e] = df[e];
        vf1[e] = df[8 + e];
        vf2[e] = df[16 + e];
    }

    // 16B-aligned PLAIN vector stores (L2 write-combine path)
    *((u16x8*)(out) + g)             = vi0;   // idx0
    *((u16x8*)(out + E) + g)         = vi1;   // idx1
    *((u16x8*)(out + 2 * E) + g)     = vd;    // dist
    u16x8* dfp = (u16x8*)(out + 3 * E) + 3 * g;   // diff
    dfp[0] = vf0; dfp[1] = vf1; dfp[2] = vf2;
    *((u16x8*)(out + 6 * E) + g)     = vv;    // valid
}

} // namespace r13

extern "C" void kernel_launch(void* const* d_in, const int* in_sizes, int n_in,
                              void* d_out, int out_size, void* d_ws, size_t ws_size,
                              hipStream_t stream) {
    using namespace r13;
    const int*   species = (const int*)d_in[0];
    const float* coords  = (const float*)d_in[1];
    const int*   cutoff  = (const int*)d_in[2];
    unsigned short* out  = (unsigned short*)d_out;

    const int groups = kP / 4;                   // 4,192,256
    const int blocks = groups / 256;             // 16,376 = 2047 * 8 exact
    fp_r13<<<blocks, 256, 0, stream>>>(species, coords, cutoff, out);
}

// Round 14
// 82.103 us; speedup vs baseline: 1.0908x; 1.0908x over previous
//
#include <hip/hip_runtime.h>

// ============================================================================
// r14 = exact revert to r12/r9 (verified best: 81.2us, 5.78 TB/s effective).
// Ablation history (all single-variable, all regressed):
//   r8  nt-stores            169.5us  (nt defeats L2 write-combine drain)
//   r10 d_ws packed table     97.4us  (per-replay rewrite kills XCD L2 reuse)
//   r11 8 ranks/thread       120.7us  (2x VGPR state, TLP halved)
//   r13 LDS molecule staging  89.6us  (b-loads were already L1 hits; barrier
//                                      + staging + lgkm deps pure overhead)
// Structure: 4 triu ranks/thread, i-atom hoisted (r7->r9: -14us), plain 16B
// u16x8 stores. 81.2us = 92% of the 6.3 TB/s copy-ceiling floor (74.5us).
//   E = 2P = 33,538,048 directed pairs; layout idx0|idx1|dist|diff*3|valid.
//   d even: (j,i), diff=c[j]-c[i];  d odd: (i,j), diff=c[i]-c[j].
// ============================================================================

namespace r14 {

constexpr int kM = 8;
constexpr int kN = 2048;
constexpr int kPPM = kN * (kN - 1) / 2;     // 2,096,128 triu pairs per molecule
constexpr int kP   = kPPM * kM;             // 16,769,024 triu pairs total
constexpr long long E = 2LL * kP;           // 33,538,048 directed pairs

typedef __attribute__((ext_vector_type(8))) unsigned short u16x8;

__device__ __forceinline__ unsigned short f2bf(float f) {
    unsigned int u = __float_as_uint(f);
    u += 0x7FFFu + ((u >> 16) & 1u);        // round-to-nearest-even
    return (unsigned short)(u >> 16);
}

__device__ __forceinline__ int row_off(int i) {
    return (i * (2 * kN - 1 - i)) >> 1;
}

__global__ __launch_bounds__(256)
void fp_r14(const int* __restrict__ species,
            const float* __restrict__ coords,
            const int* __restrict__ cutw,
            unsigned short* __restrict__ out)
{
#pragma clang fp contract(off)
    const int g = blockIdx.x * 256 + threadIdx.x;   // group of 4 triu ranks
    const int t0 = g * 4;
    if (t0 >= kP) return;

    const int m = t0 / kPPM;                // 4 | kPPM -> group never crosses mol
    const int r0 = t0 - m * kPPM;

    // invert triangular index (4095^2 = 16,769,025 exact in f32)
    const float s = (float)(16769025 - 8 * r0);
    int i = (int)floorf((4095.0f - sqrtf(s)) * 0.5f);
    i = min(max(i, 0), kN - 2);
    while (row_off(i) > r0) --i;
    while (row_off(i + 1) <= r0) ++i;
    int j = i + 1 + (r0 - row_off(i));

    // cutoff: robust decode (int32 / int64-low-word / float32)
    const int w0 = cutw[0];
    const float cutoff = (w0 > 0 && w0 < (1 << 20)) ? (float)w0 : __int_as_float(w0);

    const int base = m * kN;

    // hoisted i-atom state (reloaded only on row wrap, ~0.4% of iterations)
    int a = base + i;
    float ax = coords[3 * a + 0], ay = coords[3 * a + 1], az = coords[3 * a + 2];
    int   sa = species[a];
    unsigned short ba = f2bf((float)a);

    u16x8 vi0, vi1, vd, vv;
    u16x8 vf0, vf1, vf2;
    unsigned short df[24];

#pragma unroll
    for (int k = 0; k < 4; ++k) {
        const int b = base + j;

        const float bx = coords[3 * b + 0], by = coords[3 * b + 1], bz = coords[3 * b + 2];
        const int   sb = species[b];

        const float dx = ax - bx;
        const float dy = ay - by;
        const float dz = az - bz;
        const float d2 = dx * dx + dy * dy + dz * dz;   // no FMA: match np exactly
        const float dist = sqrtf(d2);

        const bool dummy = (sa == -1) || (sb == -1);
        const bool valid = (dist <= cutoff) && !dummy;

        const unsigned short bb = f2bf((float)b);
        const unsigned short bd = valid ? f2bf(dist) : (unsigned short)0;
        const unsigned short bv = valid ? (unsigned short)0x3F80 : (unsigned short)0;
        const unsigned short fx = valid ? f2bf(dx) : (unsigned short)0;   // fwd (i,j)
        const unsigned short fy = valid ? f2bf(dy) : (unsigned short)0;
        const unsigned short fz = valid ? f2bf(dz) : (unsigned short)0;
        const unsigned short gx = valid ? (unsigned short)(fx ^ 0x8000) : (unsigned short)0;
        const unsigned short gy = valid ? (unsigned short)(fy ^ 0x8000) : (unsigned short)0;
        const unsigned short gz = valid ? (unsigned short)(fz ^ 0x8000) : (unsigned short)0;

        // REV first (slot 2k): (j,i), diff = -(fwd); FWD second (slot 2k+1)
        vi0[2 * k]     = bb;  vi0[2 * k + 1] = ba;
        vi1[2 * k]     = ba;  vi1[2 * k + 1] = bb;
        vd[2 * k]      = bd;  vd[2 * k + 1]  = bd;
        vv[2 * k]      = bv;  vv[2 * k + 1]  = bv;
        df[6 * k + 0] = gx;  df[6 * k + 1] = gy;  df[6 * k + 2] = gz;
        df[6 * k + 3] = fx;  df[6 * k + 4] = fy;  df[6 * k + 5] = fz;

        // advance to next triu rank; reload hoisted i-state on row wrap
        ++j;
        if (j == kN) {
            ++i; j = i + 1;
            if (k < 3) {
                a = base + i;
                ax = coords[3 * a + 0]; ay = coords[3 * a + 1]; az = coords[3 * a + 2];
                sa = species[a];
                ba = f2bf((float)a);
            }
        }
    }

#pragma unroll
    for (int e = 0; e < 8; ++e) {
        vf0[e] = df[e];
        vf1[e] = df[8 + e];
        vf2[e] = df[16 + e];
    }

    // 16B-aligned PLAIN vector stores (L2 write-combine path)
    *((u16x8*)(out) + g)             = vi0;   // idx0
    *((u16x8*)(out + E) + g)         = vi1;   // idx1
    *((u16x8*)(out + 2 * E) + g)     = vd;    // dist
    u16x8* dfp = (u16x8*)(out + 3 * E) + 3 * g;   // diff
    dfp[0] = vf0; dfp[1] = vf1; dfp[2] = vf2;
    *((u16x8*)(out + 6 * E) + g)     = vv;    // valid
}

} // namespace r14

extern "C" void kernel_launch(void* const* d_in, const int* in_sizes, int n_in,
                              void* d_out, int out_size, void* d_ws, size_t ws_size,
                              hipStream_t stream) {
    using namespace r14;
    const int*   species = (const int*)d_in[0];
    const float* coords  = (const float*)d_in[1];
    const int*   cutoff  = (const int*)d_in[2];
    unsigned short* out  = (unsigned short*)d_out;

    const int groups = kP / 4;                   // 4,192,256
    const int blocks = groups / 256;             // 16,376 exact
    fp_r14<<<blocks, 256, 0, stream>>>(species, coords, cutoff, out);
}